// Round 1
// baseline (388.262 us; speedup 1.0000x reference)
//
#include <hip/hip_runtime.h>
#include <hip/hip_bf16.h>

#define LSEQ 512
#define BATCH 256
#define DIM 256
#define WMAX 128

// One block per batch row. 256 threads; thread t owns dim d=t in the main loop.
__global__ __launch_bounds__(256) void word_pool_kernel(
    const float* __restrict__ feats,     // [L, B, D]
    const int* __restrict__ word_ids,    // [B, L]
    const int* __restrict__ amask,       // [B, L]
    float* __restrict__ out)             // [W*B*D] word_feats ++ [W*B] masks
{
    const int b = blockIdx.x;
    const int t = threadIdx.x;

    __shared__ int sids[LSEQ];
    __shared__ int scount[WMAX];
    __shared__ int sstart[WMAX];
    __shared__ int s_masksum;
    __shared__ int s_maxid;

    if (t == 0) { s_masksum = 0; s_maxid = 0; }
    if (t < WMAX) scount[t] = 0;
    __syncthreads();

    // Stage word_ids row into LDS; accumulate mask sum and max id.
    int msum = 0;
    int mymax = 0;
    for (int p = t; p < LSEQ; p += 256) {
        int id = word_ids[b * LSEQ + p];
        sids[p] = id;
        mymax = max(mymax, id);
        msum += amask[b * LSEQ + p];
    }
    atomicAdd(&s_masksum, msum);
    atomicMax(&s_maxid, mymax);
    __syncthreads();

    const int char_num = s_masksum - 2;
    const int word_num = s_maxid + 1;           // <= WMAX by construction
    int pend = 1 + char_num;                    // valid positions: [1, pend)
    if (pend > LSEQ) pend = LSEQ;

    // Histogram of valid positions (ids are sorted -> contiguous runs).
    for (int p = 1 + t; p < pend; p += 256) {
        int id = sids[p];
        if (id >= 0 && id < WMAX) atomicAdd(&scount[id], 1);
    }
    __syncthreads();

    // Exclusive prefix sum over counts -> run start positions (serial; tiny).
    if (t == 0) {
        int acc = 1;  // first valid position
        for (int w = 0; w < WMAX; w++) { sstart[w] = acc; acc += scount[w]; }
    }
    __syncthreads();

    // Main loop: thread t = dim d. feats[p, b, d] = p*B*D + b*D + d.
    const int d = t;
    const float* fb = feats + (size_t)b * DIM + d;
    const size_t rowstride = (size_t)BATCH * DIM;
    float* ob = out + (size_t)b * DIM + d;

    for (int w = 0; w < WMAX; w++) {
        const int c = scount[w];
        const int base = sstart[w];
        float acc = 0.0f;
        for (int i = 0; i < c; i++) {
            acc += fb[(size_t)(base + i) * rowstride];
        }
        float val = 0.0f;
        if (w < word_num) {
            val = acc / (float)(c > 0 ? c : 1);
        }
        ob[(size_t)w * rowstride] = val;
    }

    // masks output: [W, B] at offset W*B*D, 1.0 where w < word_num.
    if (t < WMAX) {
        out[(size_t)WMAX * BATCH * DIM + (size_t)t * BATCH + b] =
            (t < word_num) ? 1.0f : 0.0f;
    }
}

extern "C" void kernel_launch(void* const* d_in, const int* in_sizes, int n_in,
                              void* d_out, int out_size, void* d_ws, size_t ws_size,
                              hipStream_t stream) {
    const float* char_feats = (const float*)d_in[0];
    const int* word_ids     = (const int*)d_in[1];
    const int* amask        = (const int*)d_in[2];
    float* out              = (float*)d_out;

    word_pool_kernel<<<BATCH, 256, 0, stream>>>(char_feats, word_ids, amask, out);
}

// Round 2
// 210.420 us; speedup vs baseline: 1.8452x; 1.8452x over previous
//
#include <hip/hip_runtime.h>
#include <hip/hip_bf16.h>

#define LSEQ 512
#define BATCH 256
#define DIM 256
#define WMAX 128
#define WPB 16          // words per block
#define BLOCKS_PER_B (WMAX / WPB)   // 8
#define ROW4 (BATCH * DIM / 4)      // feats row stride in float4 units
#define BD4 (DIM / 4)               // batch stride in float4 units

// Grid: BATCH * 8 blocks. Block 256 threads = 4 waves.
// Each block: batch b = blockIdx>>3, word chunk = (blockIdx&7)*16.
// Wave wi handles words wbase+wi, wbase+wi+4, ... (4 words per wave).
// Lane l loads float4 at dim 4*l.
__global__ __launch_bounds__(256) void word_pool_kernel(
    const float* __restrict__ feats,     // [L, B, D]
    const int* __restrict__ word_ids,    // [B, L]
    const int* __restrict__ amask,       // [B, L]
    float* __restrict__ out)             // [W*B*D] word_feats ++ [W*B] masks
{
    const int b = blockIdx.x >> 3;
    const int wbase = (blockIdx.x & 7) * WPB;
    const int t = threadIdx.x;

    __shared__ int sids[LSEQ];
    __shared__ int scount[WMAX];
    __shared__ int scum[WMAX];
    __shared__ int sstart[WMAX];
    __shared__ int s_masksum;

    if (t == 0) s_masksum = 0;
    if (t < WMAX) scount[t] = 0;
    __syncthreads();

    // Stage word_ids row into LDS; accumulate mask sum.
    int msum = 0;
    for (int p = t; p < LSEQ; p += 256) {
        sids[p] = word_ids[b * LSEQ + p];
        msum += amask[b * LSEQ + p];
    }
    atomicAdd(&s_masksum, msum);
    __syncthreads();

    const int char_num = s_masksum - 2;
    const int word_num = sids[LSEQ - 1] + 1;    // ids sorted non-decreasing
    int pend = 1 + char_num;                    // valid positions: [1, pend)
    if (pend > LSEQ) pend = LSEQ;

    // Histogram of valid positions (ids sorted -> contiguous runs).
    for (int p = 1 + t; p < pend; p += 256) {
        atomicAdd(&scount[sids[p]], 1);
    }
    __syncthreads();

    // Inclusive Hillis-Steele scan over counts (t<128 active, 7 steps).
    if (t < WMAX) scum[t] = scount[t];
    __syncthreads();
    #pragma unroll
    for (int off = 1; off < WMAX; off <<= 1) {
        int add = 0;
        if (t < WMAX && t >= off) add = scum[t - off];
        __syncthreads();
        if (t < WMAX) scum[t] += add;
        __syncthreads();
    }
    if (t < WMAX) sstart[t] = 1 + (t > 0 ? scum[t - 1] : 0);
    __syncthreads();

    // Main loop: wave wi owns words wbase+wi+4k; lane covers 4 dims (float4).
    const int lane = t & 63;
    const int wi = t >> 6;
    const float4* __restrict__ f4 = (const float4*)feats;
    float4* __restrict__ o4 = (float4*)out;
    const int boff = b * BD4 + lane;

    for (int w = wbase + wi; w < wbase + WPB; w += 4) {
        const int c = scount[w];
        const int base = sstart[w];
        float4 acc = make_float4(0.f, 0.f, 0.f, 0.f);
        #pragma unroll 4
        for (int i = 0; i < c; i++) {
            float4 v = f4[(size_t)(base + i) * ROW4 + boff];
            acc.x += v.x; acc.y += v.y; acc.z += v.z; acc.w += v.w;
        }
        // For w >= word_num, c==0 -> acc==0 -> val==0, matching the reference.
        const float inv = 1.0f / (float)(c > 0 ? c : 1);
        float4 val = make_float4(acc.x * inv, acc.y * inv, acc.z * inv, acc.w * inv);
        o4[(size_t)w * ROW4 + boff] = val;
    }

    // masks output: [W, B] at offset W*B*D; only chunk-0 block writes.
    if (wbase == 0 && t < WMAX) {
        out[(size_t)WMAX * BATCH * DIM + (size_t)t * BATCH + b] =
            (t < word_num) ? 1.0f : 0.0f;
    }
}

extern "C" void kernel_launch(void* const* d_in, const int* in_sizes, int n_in,
                              void* d_out, int out_size, void* d_ws, size_t ws_size,
                              hipStream_t stream) {
    const float* char_feats = (const float*)d_in[0];
    const int* word_ids     = (const int*)d_in[1];
    const int* amask        = (const int*)d_in[2];
    float* out              = (float*)d_out;

    word_pool_kernel<<<BATCH * BLOCKS_PER_B, 256, 0, stream>>>(
        char_feats, word_ids, amask, out);
}

// Round 3
// 207.917 us; speedup vs baseline: 1.8674x; 1.0120x over previous
//
#include <hip/hip_runtime.h>
#include <hip/hip_bf16.h>

#define LSEQ 512
#define BATCH 256
#define DIM 256
#define WMAX 128
#define NCHUNK 8
#define ROW4 (BATCH * DIM / 4)   // feats row stride in float4 units
#define BD4 (DIM / 4)            // batch stride in float4 units

// Grid: BATCH * 8 blocks of 256 threads (4 waves).
// Block = (batch b, position-chunk). Words are assigned as contiguous,
// position-balanced ranges: block chunk k owns words starting in
// [1 + k*(pend-1)/8, 1 + (k+1)*(pend-1)/8); each wave takes a quartile.
// Each wave streams its contiguous row range with a 2x4-row pipeline.
__global__ __launch_bounds__(256) void word_pool_kernel(
    const float* __restrict__ feats,     // [L, B, D]
    const int* __restrict__ word_ids,    // [B, L]
    const int* __restrict__ amask,       // [B, L]
    float* __restrict__ out)             // [W*B*D] word_feats ++ [W*B] masks
{
    const int b = blockIdx.x >> 3;
    const int chunk = blockIdx.x & 7;
    const int t = threadIdx.x;
    const int lane = t & 63;
    const int wi = t >> 6;

    __shared__ int sids[LSEQ];
    __shared__ int sstart[WMAX + 1];
    __shared__ int spart[4];

    // ---- Phase A: stage ids (waves 0-1) / mask partial sums (waves 2-3) ----
    int msum = 0;
    if (t < 128) {
        int4 q = ((const int4*)(word_ids + b * LSEQ))[t];
        ((int4*)sids)[t] = q;
    } else {
        int4 m = ((const int4*)(amask + b * LSEQ))[t - 128];
        msum = m.x + m.y + m.z + m.w;
    }
    #pragma unroll
    for (int off = 32; off; off >>= 1) msum += __shfl_down(msum, off, 64);
    if (lane == 0) spart[wi] = msum;
    __syncthreads();

    const int char_num = spart[0] + spart[1] + spart[2] + spart[3] - 2;
    int pend = 1 + char_num;               // valid positions: [1, pend)
    if (pend < 1) pend = 1;
    if (pend > LSEQ) pend = LSEQ;

    // ---- Phase B: init starts to sentinel ----
    if (t <= WMAX) sstart[t] = pend;
    __syncthreads();

    // ---- Phase C: boundary detect (ids sorted+densified -> run starts) ----
    for (int p = 1 + t; p < pend; p += 256) {
        if (p == 1 || sids[p] != sids[p - 1]) sstart[sids[p]] = p;
    }
    if (t == 0) sstart[0] = 1;   // word 0 may have zero valid chars
    __syncthreads();

    // first word whose run starts at or after pos (consistent partitioner)
    auto word_at = [&](int pos) -> int {
        if (pos >= pend) return sids[pend - 1] + 1;
        int w = sids[pos];
        return (sstart[w] >= pos) ? w : w + 1;
    };

    const int pend1 = pend - 1;
    const int P0 = 1 + (chunk * pend1) / NCHUNK;
    const int P1 = 1 + ((chunk + 1) * pend1) / NCHUNK;
    const int span = P1 - P0;
    const int Q0 = P0 + (wi * span) / 4;
    const int Q1 = P0 + ((wi + 1) * span) / 4;

    int w0 = (chunk == 0 && wi == 0) ? 0 : word_at(Q0);
    int w1 = (chunk == NCHUNK - 1 && wi == 3) ? WMAX : word_at(Q1);

    const float4* __restrict__ f4 = (const float4*)feats;
    float4* __restrict__ o4 = (float4*)out;
    const int boff = b * BD4 + lane;

    const int p_lo = sstart[w0];
    const int p_hi = sstart[w1];           // rows of [w0,w1) = [p_lo, p_hi)

    int cur = w0;
    int nxt = (cur < w1) ? sstart[cur + 1] : 0;
    float4 acc = make_float4(0.f, 0.f, 0.f, 0.f);
    int p = p_lo;

    auto ldrow = [&](int r) -> float4 {
        int rr = r < p_hi ? r : p_hi - 1;  // clamp: value discarded by logic
        return f4[(size_t)rr * ROW4 + boff];
    };

    float4 va0, va1, va2, va3;
    if (p < p_hi) { va0 = ldrow(p); va1 = ldrow(p+1); va2 = ldrow(p+2); va3 = ldrow(p+3); }

    while (p < p_hi) {
        float4 vb0, vb1, vb2, vb3;
        if (p + 4 < p_hi) { vb0 = ldrow(p+4); vb1 = ldrow(p+5); vb2 = ldrow(p+6); vb3 = ldrow(p+7); }
        #pragma unroll
        for (int j = 0; j < 4; j++) {
            int pp = p + j;
            if (pp >= p_hi) break;
            while (pp >= nxt) {            // finalize words ending at/before pp
                int c = nxt - sstart[cur];
                float inv = 1.0f / (float)(c > 0 ? c : 1);
                o4[(size_t)cur * ROW4 + boff] =
                    make_float4(acc.x * inv, acc.y * inv, acc.z * inv, acc.w * inv);
                acc = make_float4(0.f, 0.f, 0.f, 0.f);
                cur++;
                nxt = sstart[cur + 1];
            }
            float4 v = (j == 0) ? va0 : (j == 1) ? va1 : (j == 2) ? va2 : va3;
            acc.x += v.x; acc.y += v.y; acc.z += v.z; acc.w += v.w;
        }
        va0 = vb0; va1 = vb1; va2 = vb2; va3 = vb3;
        p += 4;
    }

    // finalize remaining words [cur, w1): last real word + zero-count tails
    while (cur < w1) {
        int c = sstart[cur + 1] - sstart[cur];
        float inv = 1.0f / (float)(c > 0 ? c : 1);
        o4[(size_t)cur * ROW4 + boff] =
            make_float4(acc.x * inv, acc.y * inv, acc.z * inv, acc.w * inv);
        acc = make_float4(0.f, 0.f, 0.f, 0.f);
        cur++;
    }

    // masks output: [W, B] at offset W*B*D; only chunk-0 block writes.
    if (chunk == 0 && t < WMAX) {
        int word_num = sids[LSEQ - 1] + 1;   // ids sorted over full row
        out[(size_t)WMAX * BATCH * DIM + (size_t)t * BATCH + b] =
            (t < word_num) ? 1.0f : 0.0f;
    }
}

extern "C" void kernel_launch(void* const* d_in, const int* in_sizes, int n_in,
                              void* d_out, int out_size, void* d_ws, size_t ws_size,
                              hipStream_t stream) {
    const float* char_feats = (const float*)d_in[0];
    const int* word_ids     = (const int*)d_in[1];
    const int* amask        = (const int*)d_in[2];
    float* out              = (float*)d_out;

    word_pool_kernel<<<BATCH * NCHUNK, 256, 0, stream>>>(
        char_feats, word_ids, amask, out);
}

// Round 4
// 207.169 us; speedup vs baseline: 1.8741x; 1.0036x over previous
//
#include <hip/hip_runtime.h>
#include <hip/hip_bf16.h>

#define LSEQ 512
#define BATCH 256
#define DIM 256
#define WMAX 128
#define ROW4 (BATCH * DIM / 4)   // feats row stride in float4 units
#define BD4 (DIM / 4)            // batch stride in float4 units
#define MSTRIDE (WMAX + 2)       // meta ints per batch in ws

// Kernel 1: one block per batch. Compute run-start positions (ids are sorted
// and densified -> run start = boundary), store sstart[0..WMAX] to ws, and
// write the masks output. No atomics, no scan.
__global__ __launch_bounds__(256) void meta_kernel(
    const int* __restrict__ word_ids,    // [B, L]
    const int* __restrict__ amask,       // [B, L]
    int* __restrict__ meta,              // [B, MSTRIDE]
    float* __restrict__ out)             // masks at offset W*B*D
{
    const int b = blockIdx.x;
    const int t = threadIdx.x;
    const int lane = t & 63;
    const int wi = t >> 6;

    __shared__ int sids[LSEQ];
    __shared__ int spart[4];
    __shared__ int sstart[WMAX + 1];

    int msum = 0;
    if (t < 128) {
        ((int4*)sids)[t] = ((const int4*)(word_ids + b * LSEQ))[t];
    } else {
        int4 m = ((const int4*)(amask + b * LSEQ))[t - 128];
        msum = m.x + m.y + m.z + m.w;
    }
    #pragma unroll
    for (int off = 32; off; off >>= 1) msum += __shfl_down(msum, off, 64);
    if (lane == 0) spart[wi] = msum;
    __syncthreads();

    const int char_num = spart[0] + spart[1] + spart[2] + spart[3] - 2;
    int pend = 1 + char_num;             // valid positions: [1, pend)
    if (pend < 1) pend = 1;
    if (pend > LSEQ) pend = LSEQ;

    if (t <= WMAX) sstart[t] = pend;     // sentinel: empty/tail words
    __syncthreads();

    for (int p = 1 + t; p < pend; p += 256) {
        if (p == 1 || sids[p] != sids[p - 1]) sstart[sids[p]] = p;
    }
    if (t == 0) sstart[0] = 1;
    __syncthreads();

    if (t <= WMAX) meta[b * MSTRIDE + t] = sstart[t];

    if (t < WMAX) {
        int word_num = sids[LSEQ - 1] + 1;   // sorted -> last element is max
        out[(size_t)WMAX * BATCH * DIM + (size_t)t * BATCH + b] =
            (t < word_num) ? 1.0f : 0.0f;
    }
}

// Kernel 2: one wave per (word, batch). No LDS, no barriers.
// Grid: BATCH*32 blocks (b-major, word-group inner for row locality),
// 256 threads = 4 waves, wave wi owns word wg*4+wi. Lane covers 4 dims.
__global__ __launch_bounds__(256) void pool_kernel(
    const float* __restrict__ feats,     // [L, B, D]
    const int* __restrict__ meta,        // [B, MSTRIDE]
    float* __restrict__ out)             // [W, B, D]
{
    const int b = blockIdx.x >> 5;
    const int wg = blockIdx.x & 31;
    const int t = threadIdx.x;
    const int lane = t & 63;
    const int w = wg * 4 + (t >> 6);

    const int* m = meta + b * MSTRIDE;
    const int s0 = m[w];
    const int s1 = m[w + 1];
    const int c = s1 - s0;               // >= 0; 0 for empty/padded words

    const float4* __restrict__ f4 = (const float4*)feats;
    const int boff = b * BD4 + lane;

    float4 acc = make_float4(0.f, 0.f, 0.f, 0.f);
    for (int i = 0; i < c; i += 8) {
        const int n = c - i;             // wave-uniform
        float4 v[8];
        #pragma unroll
        for (int j = 0; j < 8; j++) {
            if (j < n) v[j] = f4[(size_t)(s0 + i + j) * ROW4 + boff];
        }
        #pragma unroll
        for (int j = 0; j < 8; j++) {
            if (j < n) {
                acc.x += v[j].x; acc.y += v[j].y;
                acc.z += v[j].z; acc.w += v[j].w;
            }
        }
    }

    const float inv = 1.0f / (float)(c > 0 ? c : 1);
    ((float4*)out)[(size_t)w * ROW4 + boff] =
        make_float4(acc.x * inv, acc.y * inv, acc.z * inv, acc.w * inv);
}

extern "C" void kernel_launch(void* const* d_in, const int* in_sizes, int n_in,
                              void* d_out, int out_size, void* d_ws, size_t ws_size,
                              hipStream_t stream) {
    const float* char_feats = (const float*)d_in[0];
    const int* word_ids     = (const int*)d_in[1];
    const int* amask        = (const int*)d_in[2];
    float* out              = (float*)d_out;
    int* meta               = (int*)d_ws;

    meta_kernel<<<BATCH, 256, 0, stream>>>(word_ids, amask, meta, out);
    pool_kernel<<<BATCH * 32, 256, 0, stream>>>(char_feats, meta, out);
}

// Round 5
// 203.478 us; speedup vs baseline: 1.9081x; 1.0181x over previous
//
#include <hip/hip_runtime.h>
#include <hip/hip_bf16.h>

#define LSEQ 512
#define BATCH 256
#define DIM 256
#define WMAX 128
#define ROW4 (BATCH * DIM / 4)   // feats row stride in float4 units
#define BD4 (DIM / 4)            // batch stride in float4 units
#define MSTRIDE (WMAX + 2)       // meta ints per batch in ws

// Kernel 1: one block per batch. Compute run-start positions (ids are sorted
// and densified -> run start = boundary), store sstart[0..WMAX] to ws, and
// write the masks output. No atomics, no scan.
__global__ __launch_bounds__(256) void meta_kernel(
    const int* __restrict__ word_ids,    // [B, L]
    const int* __restrict__ amask,       // [B, L]
    int* __restrict__ meta,              // [B, MSTRIDE]
    float* __restrict__ out)             // masks at offset W*B*D
{
    const int b = blockIdx.x;
    const int t = threadIdx.x;
    const int lane = t & 63;
    const int wi = t >> 6;

    __shared__ int sids[LSEQ];
    __shared__ int spart[4];
    __shared__ int sstart[WMAX + 1];

    int msum = 0;
    if (t < 128) {
        ((int4*)sids)[t] = ((const int4*)(word_ids + b * LSEQ))[t];
    } else {
        int4 m = ((const int4*)(amask + b * LSEQ))[t - 128];
        msum = m.x + m.y + m.z + m.w;
    }
    #pragma unroll
    for (int off = 32; off; off >>= 1) msum += __shfl_down(msum, off, 64);
    if (lane == 0) spart[wi] = msum;
    __syncthreads();

    const int char_num = spart[0] + spart[1] + spart[2] + spart[3] - 2;
    int pend = 1 + char_num;             // valid positions: [1, pend)
    if (pend < 1) pend = 1;
    if (pend > LSEQ) pend = LSEQ;

    if (t <= WMAX) sstart[t] = pend;     // sentinel: empty/tail words
    __syncthreads();

    for (int p = 1 + t; p < pend; p += 256) {
        if (p == 1 || sids[p] != sids[p - 1]) sstart[sids[p]] = p;
    }
    if (t == 0) sstart[0] = 1;
    __syncthreads();

    if (t <= WMAX) meta[b * MSTRIDE + t] = sstart[t];

    if (t < WMAX) {
        int word_num = sids[LSEQ - 1] + 1;   // sorted -> last element is max
        out[(size_t)WMAX * BATCH * DIM + (size_t)t * BATCH + b] =
            (t < word_num) ? 1.0f : 0.0f;
    }
}

// Kernel 2: one wave per (word, batch). No LDS, no barriers.
// Grid order is WORD-GROUP-MAJOR: blockIdx = wg*BATCH + b, so the ~2048
// resident blocks cover ALL batches of a narrow row window -> each 256KB
// feats row is consumed contiguously in a tight time span (page locality).
__global__ __launch_bounds__(256) void pool_kernel(
    const float* __restrict__ feats,     // [L, B, D]
    const int* __restrict__ meta,        // [B, MSTRIDE]
    float* __restrict__ out)             // [W, B, D]
{
    const int b = blockIdx.x & (BATCH - 1);
    const int wg = blockIdx.x >> 8;
    const int t = threadIdx.x;
    const int lane = t & 63;
    const int w = wg * 4 + (t >> 6);

    const int* m = meta + b * MSTRIDE;
    const int s0 = m[w];
    const int s1 = m[w + 1];
    const int c = s1 - s0;               // >= 0; 0 for empty/padded words

    const float4* __restrict__ f4 = (const float4*)feats;
    const int boff = b * BD4 + lane;

    float4 acc = make_float4(0.f, 0.f, 0.f, 0.f);
    for (int i = 0; i < c; i += 8) {
        const int n = c - i;             // wave-uniform
        float4 v[8];
        #pragma unroll
        for (int j = 0; j < 8; j++) {
            if (j < n) v[j] = f4[(size_t)(s0 + i + j) * ROW4 + boff];
        }
        #pragma unroll
        for (int j = 0; j < 8; j++) {
            if (j < n) {
                acc.x += v[j].x; acc.y += v[j].y;
                acc.z += v[j].z; acc.w += v[j].w;
            }
        }
    }

    const float inv = 1.0f / (float)(c > 0 ? c : 1);
    ((float4*)out)[(size_t)w * ROW4 + boff] =
        make_float4(acc.x * inv, acc.y * inv, acc.z * inv, acc.w * inv);
}

extern "C" void kernel_launch(void* const* d_in, const int* in_sizes, int n_in,
                              void* d_out, int out_size, void* d_ws, size_t ws_size,
                              hipStream_t stream) {
    const float* char_feats = (const float*)d_in[0];
    const int* word_ids     = (const int*)d_in[1];
    const int* amask        = (const int*)d_in[2];
    float* out              = (float*)d_out;
    int* meta               = (int*)d_ws;

    meta_kernel<<<BATCH, 256, 0, stream>>>(word_ids, amask, meta, out);
    pool_kernel<<<BATCH * 32, 256, 0, stream>>>(char_feats, meta, out);
}